// Round 11
// baseline (194.283 us; speedup 1.0000x reference)
//
#include <hip/hip_runtime.h>
#include <hip/hip_bf16.h>

// NA Spatial MSA, fused:  out = attn @ (xw @ (Wv@Wo)) + bo
// R11 = R10 + XCD-bijective block swizzle (T1). R10 proved desynced
// multi-block demand lifts BW to 3.05 TB/s, but sibling (window, ch-half)
// blocks landed on different XCDs -> x+attn fetched twice (FETCH 328MB).
// Swizzle: xcd = i&7, j = i>>3, w = xcd*512 + (j>>1), chalf = j&1 ->
// siblings adjacent on the SAME XCD; second block's reads hit its L2.

typedef __bf16 bf16x8 __attribute__((ext_vector_type(8)));
typedef __bf16 bf16x4 __attribute__((ext_vector_type(4)));
typedef float  f32x16 __attribute__((ext_vector_type(16)));
typedef float  f32x4  __attribute__((ext_vector_type(4)));
typedef unsigned int uint;
typedef uint   uint4v __attribute__((ext_vector_type(4)));

#define MFMA32(a, b, c) __builtin_amdgcn_mfma_f32_32x32x16_bf16(a, b, c, 0, 0, 0)

// ---------------- Stage 0: WT = (Wv @ Wo)^T in bf16 ----------------
__global__ void wfuse_kernel(const float* __restrict__ Wv,
                             const float* __restrict__ Wo,
                             __bf16* __restrict__ WT) {
  const int n = blockIdx.x;
  const int k = threadIdx.x;
  const float* wvrow = Wv + k * 256;
  float acc = 0.f;
#pragma unroll 4
  for (int j = 0; j < 256; j += 4) {
    f32x4 wv = *(const f32x4*)(wvrow + j);
    acc += wv.x * Wo[(j + 0) * 256 + n];
    acc += wv.y * Wo[(j + 1) * 256 + n];
    acc += wv.z * Wo[(j + 2) * 256 + n];
    acc += wv.w * Wo[(j + 3) * 256 + n];
  }
  WT[n * 256 + k] = (__bf16)acc;
}

static __device__ __forceinline__ uint pkbf(float lo, float hi) {
  return (uint)__builtin_bit_cast(unsigned short, (__bf16)lo) |
         ((uint)__builtin_bit_cast(unsigned short, (__bf16)hi) << 16);
}

// GEMM2 B-frags from GEMM1 acc via pack + shfl_xor(32). (verified R3/R5/R7)
static __device__ __forceinline__ void build_bfrags(const f32x16 acc, int lh,
                                                    bf16x8* bf) {
  uint wd0 = pkbf(acc[0],  acc[1]);
  uint wd1 = pkbf(acc[2],  acc[3]);
  uint wd2 = pkbf(acc[4],  acc[5]);
  uint wd3 = pkbf(acc[6],  acc[7]);
  uint wd4 = pkbf(acc[8],  acc[9]);
  uint wd5 = pkbf(acc[10], acc[11]);
  uint wd6 = pkbf(acc[12], acc[13]);
  uint wd7 = pkbf(acc[14], acc[15]);
  {
    uint o0 = (uint)__shfl_xor((int)wd2, 32);
    uint o1 = (uint)__shfl_xor((int)wd3, 32);
    uint o2 = (uint)__shfl_xor((int)wd0, 32);
    uint o3 = (uint)__shfl_xor((int)wd1, 32);
    uint4v uv = { lh ? o0 : wd0, lh ? o1 : wd1,
                  lh ? wd2 : o2, lh ? wd3 : o3 };
    bf[0] = __builtin_bit_cast(bf16x8, uv);
  }
  {
    uint o0 = (uint)__shfl_xor((int)wd6, 32);
    uint o1 = (uint)__shfl_xor((int)wd7, 32);
    uint o2 = (uint)__shfl_xor((int)wd4, 32);
    uint o3 = (uint)__shfl_xor((int)wd5, 32);
    uint4v uv = { lh ? o0 : wd4, lh ? o1 : wd5,
                  lh ? wd6 : o2, lh ? wd7 : o3 };
    bf[1] = __builtin_bit_cast(bf16x8, uv);
  }
}

static __device__ __forceinline__ long wbase(int w) {
  int wi = w & 31;
  int hi = (w >> 5) & 31;
  int b  = w >> 10;
  return (((long)(b * 256 + hi * 8)) * 256 + wi * 8) * 256;
}

// async 16B/lane global->LDS DMA (LDS dest = wave-uniform base + lane*16)
static __device__ __forceinline__ void dma16(const float* gp, char* lp) {
  __builtin_amdgcn_global_load_lds(
      (const __attribute__((address_space(1))) uint*)gp,
      (__attribute__((address_space(3))) uint*)lp, 16, 0, 0);
}

// read bf16x8 A-frag from half-K f32 x strip: tok row = 512B, granule g
// (16B) lives at slot g ^ (tok&31).  g = local_k/4, needs g and g+1 (g<=30).
static __device__ __forceinline__ bf16x8 ldax_h(const char* xs, int tok, int g) {
  const int sw = tok & 31;
  f32x4 u = *(const f32x4*)(xs + tok * 512 + ((g ^ sw) << 4));
  f32x4 v = *(const f32x4*)(xs + tok * 512 + (((g + 1) ^ sw) << 4));
  bf16x8 r;
  r[0] = (__bf16)u.x; r[1] = (__bf16)u.y; r[2] = (__bf16)u.z; r[3] = (__bf16)u.w;
  r[4] = (__bf16)v.x; r[5] = (__bf16)v.y; r[6] = (__bf16)v.z; r[7] = (__bf16)v.w;
  return r;
}

// ---------------- Main kernel ----------------
// LDS 40KB: [0,32K) x half-K f32 (staged twice); [32K,40K) attn bf16.
__global__ __launch_bounds__(256)
void na_msa_kernel(const float* __restrict__ x,
                   const float* __restrict__ attn,
                   const __bf16* __restrict__ WT,
                   const float* __restrict__ bo,
                   float* __restrict__ out) {
  __shared__ char lds[40960];
  char* lds_at = lds + 32768;

  const int t    = threadIdx.x;
  const int lane = t & 63;
  const int wvi  = t >> 6;              // wave 0..3, owns 32 ch
  const int ln31 = lane & 31;
  const int lh   = lane >> 5;

  // ---- XCD-bijective swizzle (THE R11 change): siblings share an XCD ----
  const int i     = blockIdx.x;
  const int xcd   = i & 7;
  const int j     = i >> 3;             // 0..1023 within this XCD
  const int w     = xcd * 512 + (j >> 1);   // window id
  const int chalf = j & 1;              // channel half (0:[0,128) 1:[128,256))

  const long base = wbase(w);
  const float* xp = x + base;
  const float* ap = attn + (long)w * 4096;

  const int chb = chalf * 128 + wvi * 32;         // wave's first channel
  const __bf16* wtp = WT + (chb + ln31) * 256 + 8 * lh;
  const float bv = bo[chb + ln31];

  // attn staging geometry: thread t handles f32x4 idx {j*256+t, j=0..3}
  const int ar = t >> 4;                // base row (j adds 16)
  const int ak0 = (t & 15) * 4;

  // ---- x K-half DMA: 32KB as 32 instrs (8/wave). Instr covers tok pair
  // tp={2tp,2tp+1}: lanes 0-31 -> even tok, 32-63 -> odd. Source granule
  // perm = (l&31)^(tok&31) pre-swizzles so linear LDS dest yields the
  // swizzled tile ldax_h expects. ----
#define STAGE_XH(KHALF) do {                                               \
    _Pragma("unroll")                                                      \
    for (int jj = 0; jj < 8; ++jj) {                                       \
      int tp_ = jj * 4 + wvi;                                              \
      int tok_ = tp_ * 2 + (lane >> 5);                                    \
      int perm_ = (lane & 31) ^ (tok_ & 31);                               \
      const float* gp_ = xp + (tok_ >> 3) * 65536 + (tok_ & 7) * 256 +     \
                         (KHALF) * 128 + perm_ * 4;                        \
      int off_ = __builtin_amdgcn_readfirstlane(tp_ * 1024);               \
      dma16(gp_, lds + off_);                                              \
    } } while (0)

  // ---- attn loads FIRST (so their vmcnt wait leaves the DMAs in flight) --
  f32x4 ra0 = *(const f32x4*)(ap + (0 * 256 + t) * 4);
  f32x4 ra1 = *(const f32x4*)(ap + (1 * 256 + t) * 4);
  f32x4 ra2 = *(const f32x4*)(ap + (2 * 256 + t) * 4);
  f32x4 ra3 = *(const f32x4*)(ap + (3 * 256 + t) * 4);
  STAGE_XH(0);

  // attn cvt + ds_write (waits only the attn loads, DMAs ride)
#define AWR(J, RA) do {                                                    \
    int row_ = (J) * 16 + ar;                                              \
    *(bf16x4*)(lds_at + row_ * 128 + ((ak0 * 2) ^ ((row_ & 7) << 4))) =    \
        bf16x4{ (__bf16)(RA).x, (__bf16)(RA).y, (__bf16)(RA).z, (__bf16)(RA).w }; \
    } while (0)
  AWR(0, ra0); AWR(1, ra1); AWR(2, ra2); AWR(3, ra3);

  asm volatile("s_waitcnt vmcnt(0) lgkmcnt(0)" ::: "memory");
  __builtin_amdgcn_s_barrier();
  __builtin_amdgcn_sched_barrier(0);

  // ---- GEMM1 first K-half: ks 0..7 (global k = ks*16 + 8lh) ----
  f32x16 acc0 = {}, acc1 = {};
#pragma unroll
  for (int ks = 0; ks < 8; ++ks) {
    int g = 4 * ks + 2 * lh;                       // granule in [0,32)
    bf16x8 a0 = ldax_h(lds, ln31, g);              // toks 0..31
    bf16x8 a1 = ldax_h(lds, 32 + ln31, g);         // toks 32..63
    bf16x8 b0 = *(const bf16x8*)(wtp + ks * 16);
    acc0 = MFMA32(a0, b0, acc0);
    acc1 = MFMA32(a1, b0, acc1);
  }

  // ---- re-stage buffer with second K-half ----
  asm volatile("s_waitcnt lgkmcnt(0)" ::: "memory");
  __builtin_amdgcn_s_barrier();                     // all waves done reading
  STAGE_XH(1);
  asm volatile("s_waitcnt vmcnt(0)" ::: "memory");
  __builtin_amdgcn_s_barrier();
  __builtin_amdgcn_sched_barrier(0);

  // ---- GEMM1 second K-half: ks 8..15 ----
#pragma unroll
  for (int ks = 8; ks < 16; ++ks) {
    int g = 4 * (ks - 8) + 2 * lh;
    bf16x8 a0 = ldax_h(lds, ln31, g);
    bf16x8 a1 = ldax_h(lds, 32 + ln31, g);
    bf16x8 b0 = *(const bf16x8*)(wtp + ks * 16);
    acc0 = MFMA32(a0, b0, acc0);
    acc1 = MFMA32(a1, b0, acc1);
  }

  // ---- GEMM2 B-frags in-register ----
  bf16x8 bfr[4];
  build_bfrags(acc0, lh, &bfr[0]);   // ks 0,1 (toks 0..31)
  build_bfrags(acc1, lh, &bfr[2]);   // ks 2,3 (toks 32..63)

  // ---- GEMM2: out[tok][ch] = attn @ z, K=64 ----
  f32x16 o0 = {}, o1 = {};
#pragma unroll
  for (int ks = 0; ks < 4; ++ks) {
    int kk = ks * 16 + 8 * lh;
    int ab0 = ln31 * 128 + ((kk * 2) ^ ((ln31 & 7) << 4));
    bf16x8 a0 = *(const bf16x8*)(lds_at + ab0);             // out-toks 0..31
    bf16x8 a1 = *(const bf16x8*)(lds_at + ab0 + 4096);      // out-toks 32..63
    o0 = MFMA32(a0, bfr[ks], o0);
    o1 = MFMA32(a1, bfr[ks], o1);
  }

  // ---- epilogue: + bo, scatter-store ----
  float* op = out + base;
  const int ch = chb + ln31;
#pragma unroll
  for (int r = 0; r < 16; ++r) {
    int tok = (r & 3) + 8 * (r >> 2) + 4 * lh;              // o0: toks 0..31
    op[(tok >> 3) * 65536 + (tok & 7) * 256 + ch] = o0[r] + bv;
  }
#pragma unroll
  for (int r = 0; r < 16; ++r) {
    int tok = 32 + (r & 3) + 8 * (r >> 2) + 4 * lh;         // o1: toks 32..63
    op[(tok >> 3) * 65536 + (tok & 7) * 256 + ch] = o1[r] + bv;
  }
#undef STAGE_XH
#undef AWR
}

extern "C" void kernel_launch(void* const* d_in, const int* in_sizes, int n_in,
                              void* d_out, int out_size, void* d_ws, size_t ws_size,
                              hipStream_t stream) {
  const float* x    = (const float*)d_in[0];
  const float* attn = (const float*)d_in[1];
  const float* Wv   = (const float*)d_in[2];
  const float* Wo   = (const float*)d_in[3];
  const float* bo   = (const float*)d_in[4];
  float* out = (float*)d_out;
  __bf16* WT = (__bf16*)d_ws;   // 256*256*2 = 128 KB scratch

  wfuse_kernel<<<256, 256, 0, stream>>>(Wv, Wo, WT);
  na_msa_kernel<<<8192, 256, 0, stream>>>(x, attn, WT, bo, out);
}

// Round 12
// 185.826 us; speedup vs baseline: 1.0455x; 1.0455x over previous
//
#include <hip/hip_runtime.h>
#include <hip/hip_bf16.h>

// NA Spatial MSA, fused:  out = attn @ (xw @ (Wv@Wo)) + bo
// R12: (window, chalf) blocks like R10/R11 BUT full-K staging -> ONE
// stage->vmcnt(0)->barrier chain per block (R10/R11 had two), XCD sibling
// swizzle retained (R11: dedups x via L2), 72KB LDS -> 2 INDEPENDENT
// blocks/CU that desync and overlap each other's staging with compute.
// A/B vs R7 (8 lockstep waves, 173us): same waves/CU, independent instead.

typedef __bf16 bf16x8 __attribute__((ext_vector_type(8)));
typedef __bf16 bf16x4 __attribute__((ext_vector_type(4)));
typedef float  f32x16 __attribute__((ext_vector_type(16)));
typedef float  f32x4  __attribute__((ext_vector_type(4)));
typedef unsigned int uint;
typedef uint   uint4v __attribute__((ext_vector_type(4)));

#define MFMA32(a, b, c) __builtin_amdgcn_mfma_f32_32x32x16_bf16(a, b, c, 0, 0, 0)

// ---------------- Stage 0: WT = (Wv @ Wo)^T in bf16 ----------------
__global__ void wfuse_kernel(const float* __restrict__ Wv,
                             const float* __restrict__ Wo,
                             __bf16* __restrict__ WT) {
  const int n = blockIdx.x;
  const int k = threadIdx.x;
  const float* wvrow = Wv + k * 256;
  float acc = 0.f;
#pragma unroll 4
  for (int j = 0; j < 256; j += 4) {
    f32x4 wv = *(const f32x4*)(wvrow + j);
    acc += wv.x * Wo[(j + 0) * 256 + n];
    acc += wv.y * Wo[(j + 1) * 256 + n];
    acc += wv.z * Wo[(j + 2) * 256 + n];
    acc += wv.w * Wo[(j + 3) * 256 + n];
  }
  WT[n * 256 + k] = (__bf16)acc;
}

static __device__ __forceinline__ uint pkbf(float lo, float hi) {
  return (uint)__builtin_bit_cast(unsigned short, (__bf16)lo) |
         ((uint)__builtin_bit_cast(unsigned short, (__bf16)hi) << 16);
}

// GEMM2 B-frags from GEMM1 acc via pack + shfl_xor(32). (verified R3/R5/R7)
static __device__ __forceinline__ void build_bfrags(const f32x16 acc, int lh,
                                                    bf16x8* bf) {
  uint wd0 = pkbf(acc[0],  acc[1]);
  uint wd1 = pkbf(acc[2],  acc[3]);
  uint wd2 = pkbf(acc[4],  acc[5]);
  uint wd3 = pkbf(acc[6],  acc[7]);
  uint wd4 = pkbf(acc[8],  acc[9]);
  uint wd5 = pkbf(acc[10], acc[11]);
  uint wd6 = pkbf(acc[12], acc[13]);
  uint wd7 = pkbf(acc[14], acc[15]);
  {
    uint o0 = (uint)__shfl_xor((int)wd2, 32);
    uint o1 = (uint)__shfl_xor((int)wd3, 32);
    uint o2 = (uint)__shfl_xor((int)wd0, 32);
    uint o3 = (uint)__shfl_xor((int)wd1, 32);
    uint4v uv = { lh ? o0 : wd0, lh ? o1 : wd1,
                  lh ? wd2 : o2, lh ? wd3 : o3 };
    bf[0] = __builtin_bit_cast(bf16x8, uv);
  }
  {
    uint o0 = (uint)__shfl_xor((int)wd6, 32);
    uint o1 = (uint)__shfl_xor((int)wd7, 32);
    uint o2 = (uint)__shfl_xor((int)wd4, 32);
    uint o3 = (uint)__shfl_xor((int)wd5, 32);
    uint4v uv = { lh ? o0 : wd4, lh ? o1 : wd5,
                  lh ? wd6 : o2, lh ? wd7 : o3 };
    bf[1] = __builtin_bit_cast(bf16x8, uv);
  }
}

static __device__ __forceinline__ long wbase(int w) {
  int wi = w & 31;
  int hi = (w >> 5) & 31;
  int b  = w >> 10;
  return (((long)(b * 256 + hi * 8)) * 256 + wi * 8) * 256;
}

// async 16B/lane global->LDS DMA (LDS dest = wave-uniform base + lane*16)
static __device__ __forceinline__ void dma16(const float* gp, char* lp) {
  __builtin_amdgcn_global_load_lds(
      (const __attribute__((address_space(1))) uint*)gp,
      (__attribute__((address_space(3))) uint*)lp, 16, 0, 0);
}

// read bf16x8 A-frag from full-K f32 x strip: tok row = 1024B, granule g
// (16B, 0..63) lives at slot g ^ (tok&31).  (R7-verified layout)
static __device__ __forceinline__ bf16x8 ldax(const char* xs, int tok, int g) {
  const int sw = tok & 31;
  f32x4 u = *(const f32x4*)(xs + tok * 1024 + ((g ^ sw) << 4));
  f32x4 v = *(const f32x4*)(xs + tok * 1024 + (((g + 1) ^ sw) << 4));
  bf16x8 r;
  r[0] = (__bf16)u.x; r[1] = (__bf16)u.y; r[2] = (__bf16)u.z; r[3] = (__bf16)u.w;
  r[4] = (__bf16)v.x; r[5] = (__bf16)v.y; r[6] = (__bf16)v.z; r[7] = (__bf16)v.w;
  return r;
}

// ---------------- Main kernel ----------------
// LDS 72KB: [0,64K) x full-K f32 (DMA, pre-swizzled src); [64K,72K) attn bf16.
__global__ __launch_bounds__(256)
void na_msa_kernel(const float* __restrict__ x,
                   const float* __restrict__ attn,
                   const __bf16* __restrict__ WT,
                   const float* __restrict__ bo,
                   float* __restrict__ out) {
  __shared__ char lds[73728];
  char* lds_at = lds + 65536;

  const int t    = threadIdx.x;
  const int lane = t & 63;
  const int wvi  = t >> 6;              // wave 0..3, owns 32 ch
  const int ln31 = lane & 31;
  const int lh   = lane >> 5;

  // ---- XCD-bijective swizzle (R11): siblings share an XCD's L2 ----
  const int i     = blockIdx.x;
  const int xcd   = i & 7;
  const int j     = i >> 3;             // 0..1023 within this XCD
  const int w     = xcd * 512 + (j >> 1);   // window id
  const int chalf = j & 1;              // channel half

  const long base = wbase(w);
  const float* xp = x + base;
  const float* ap = attn + (long)w * 4096;

  const int chb = chalf * 128 + wvi * 32;         // wave's first channel
  const __bf16* wtp = WT + (chb + ln31) * 256 + 8 * lh;
  const float bv = bo[chb + ln31];

  // attn staging geometry: thread t handles f32x4 idx {j*256+t, j=0..3}
  const int ar = t >> 4;                // base row (j adds 16)
  const int ak0 = (t & 15) * 4;

  // ---- attn loads FIRST (oldest VMEM ops: waiting for them leaves the
  // newer DMAs in flight) ----
  f32x4 ra0 = *(const f32x4*)(ap + (0 * 256 + t) * 4);
  f32x4 ra1 = *(const f32x4*)(ap + (1 * 256 + t) * 4);
  f32x4 ra2 = *(const f32x4*)(ap + (2 * 256 + t) * 4);
  f32x4 ra3 = *(const f32x4*)(ap + (3 * 256 + t) * 4);

  // ---- x full-K DMA: 64KB as 64 instrs (16/wave, one 1KB tok-row each).
  // Source granule perm = lane ^ (tok&31) pre-swizzles so the linear LDS
  // dest yields the swizzled tile ldax expects. ----
#pragma unroll
  for (int jj = 0; jj < 16; ++jj) {
    int tok_ = jj * 4 + wvi;
    int perm_ = lane ^ (tok_ & 31);
    const float* gp_ = xp + (tok_ >> 3) * 65536 + (tok_ & 7) * 256 + perm_ * 4;
    int off_ = __builtin_amdgcn_readfirstlane(tok_ * 1024);
    dma16(gp_, lds + off_);
  }

  // ---- attn cvt + ds_write (compiler waits only the attn loads) ----
#define AWR(J, RA) do {                                                    \
    int row_ = (J) * 16 + ar;                                              \
    *(bf16x4*)(lds_at + row_ * 128 + ((ak0 * 2) ^ ((row_ & 7) << 4))) =    \
        bf16x4{ (__bf16)(RA).x, (__bf16)(RA).y, (__bf16)(RA).z, (__bf16)(RA).w }; \
    } while (0)
  AWR(0, ra0); AWR(1, ra1); AWR(2, ra2); AWR(3, ra3);
#undef AWR

  // ---- the ONE staging drain of this block ----
  asm volatile("s_waitcnt vmcnt(0) lgkmcnt(0)" ::: "memory");
  __builtin_amdgcn_s_barrier();
  __builtin_amdgcn_sched_barrier(0);

  // ---- GEMM1: z[tok][ch] = xw @ W, K=256 ----
  f32x16 acc0 = {}, acc1 = {};
#pragma unroll 4
  for (int ks = 0; ks < 16; ++ks) {
    int g = 4 * ks + 2 * lh;                       // granule in [0,64)
    bf16x8 a0 = ldax(lds, ln31, g);                // toks 0..31
    bf16x8 a1 = ldax(lds, 32 + ln31, g);           // toks 32..63
    bf16x8 b0 = *(const bf16x8*)(wtp + ks * 16);   // L1/L2-resident
    acc0 = MFMA32(a0, b0, acc0);
    acc1 = MFMA32(a1, b0, acc1);
  }

  // ---- GEMM2 B-frags in-register ----
  bf16x8 bfr[4];
  build_bfrags(acc0, lh, &bfr[0]);   // ks 0,1 (toks 0..31)
  build_bfrags(acc1, lh, &bfr[2]);   // ks 2,3 (toks 32..63)

  // ---- GEMM2: out[tok][ch] = attn @ z, K=64 ----
  f32x16 o0 = {}, o1 = {};
#pragma unroll
  for (int ks = 0; ks < 4; ++ks) {
    int kk = ks * 16 + 8 * lh;
    int ab0 = ln31 * 128 + ((kk * 2) ^ ((ln31 & 7) << 4));
    bf16x8 a0 = *(const bf16x8*)(lds_at + ab0);             // out-toks 0..31
    bf16x8 a1 = *(const bf16x8*)(lds_at + ab0 + 4096);      // out-toks 32..63
    o0 = MFMA32(a0, bfr[ks], o0);
    o1 = MFMA32(a1, bfr[ks], o1);
  }

  // ---- epilogue: + bo, scatter-store ----
  float* op = out + base;
  const int ch = chb + ln31;
#pragma unroll
  for (int r = 0; r < 16; ++r) {
    int tok = (r & 3) + 8 * (r >> 2) + 4 * lh;              // o0: toks 0..31
    op[(tok >> 3) * 65536 + (tok & 7) * 256 + ch] = o0[r] + bv;
  }
#pragma unroll
  for (int r = 0; r < 16; ++r) {
    int tok = 32 + (r & 3) + 8 * (r >> 2) + 4 * lh;         // o1: toks 32..63
    op[(tok >> 3) * 65536 + (tok & 7) * 256 + ch] = o1[r] + bv;
  }
}

extern "C" void kernel_launch(void* const* d_in, const int* in_sizes, int n_in,
                              void* d_out, int out_size, void* d_ws, size_t ws_size,
                              hipStream_t stream) {
  const float* x    = (const float*)d_in[0];
  const float* attn = (const float*)d_in[1];
  const float* Wv   = (const float*)d_in[2];
  const float* Wo   = (const float*)d_in[3];
  const float* bo   = (const float*)d_in[4];
  float* out = (float*)d_out;
  __bf16* WT = (__bf16*)d_ws;   // 256*256*2 = 128 KB scratch

  wfuse_kernel<<<256, 256, 0, stream>>>(Wv, Wo, WT);
  na_msa_kernel<<<8192, 256, 0, stream>>>(x, attn, WT, bo, out);
}

// Round 13
// 157.861 us; speedup vs baseline: 1.2307x; 1.1771x over previous
//
#include <hip/hip_runtime.h>
#include <hip/hip_bf16.h>

// NA Spatial MSA, fused:  out = attn @ (xw @ (Wv@Wo)) + bo
// R13 = R7 + the vmcnt-interference fix:
//  (1) WT b0 fragments are LOOP-INVARIANT (wave's fixed 32 ch) -> hoisted to
//      64 VGPRs in the prologue. Steady-state loop has ZERO compiler-tracked
//      global loads -> no compiler s_waitcnt vmcnt in GEMM1/GEMM2 -> the
//      next-window DMAs (older in vmcnt FIFO) are never force-retired.
//      (R7-R12: every b0 use emitted vmcnt(N); in-order retirement dragged
//      the DMAs with it -> stage serialized into compute -> 10.8us/window.)
//  (2) attn(w+1) load+cvt+ds_write moved BEFORE the DMA issue (its wait
//      can only see the attn loads).
//  (3) loop-end: vmcnt(32) -> 32 stores ride the barrier, DMAs forced done.

typedef __bf16 bf16x8 __attribute__((ext_vector_type(8)));
typedef __bf16 bf16x4 __attribute__((ext_vector_type(4)));
typedef float  f32x16 __attribute__((ext_vector_type(16)));
typedef float  f32x4  __attribute__((ext_vector_type(4)));
typedef unsigned int uint;
typedef uint   uint4v __attribute__((ext_vector_type(4)));

#define MFMA32(a, b, c) __builtin_amdgcn_mfma_f32_32x32x16_bf16(a, b, c, 0, 0, 0)

// ---------------- Stage 0: WT = (Wv @ Wo)^T in bf16 ----------------
__global__ void wfuse_kernel(const float* __restrict__ Wv,
                             const float* __restrict__ Wo,
                             __bf16* __restrict__ WT) {
  const int n = blockIdx.x;
  const int k = threadIdx.x;
  const float* wvrow = Wv + k * 256;
  float acc = 0.f;
#pragma unroll 4
  for (int j = 0; j < 256; j += 4) {
    f32x4 wv = *(const f32x4*)(wvrow + j);
    acc += wv.x * Wo[(j + 0) * 256 + n];
    acc += wv.y * Wo[(j + 1) * 256 + n];
    acc += wv.z * Wo[(j + 2) * 256 + n];
    acc += wv.w * Wo[(j + 3) * 256 + n];
  }
  WT[n * 256 + k] = (__bf16)acc;
}

static __device__ __forceinline__ uint pkbf(float lo, float hi) {
  return (uint)__builtin_bit_cast(unsigned short, (__bf16)lo) |
         ((uint)__builtin_bit_cast(unsigned short, (__bf16)hi) << 16);
}

// GEMM2 B-frags from GEMM1 acc via pack + shfl_xor(32). (verified R3/R5/R7)
static __device__ __forceinline__ void build_bfrags(const f32x16 acc, int lh,
                                                    bf16x8* bf) {
  uint wd0 = pkbf(acc[0],  acc[1]);
  uint wd1 = pkbf(acc[2],  acc[3]);
  uint wd2 = pkbf(acc[4],  acc[5]);
  uint wd3 = pkbf(acc[6],  acc[7]);
  uint wd4 = pkbf(acc[8],  acc[9]);
  uint wd5 = pkbf(acc[10], acc[11]);
  uint wd6 = pkbf(acc[12], acc[13]);
  uint wd7 = pkbf(acc[14], acc[15]);
  {
    uint o0 = (uint)__shfl_xor((int)wd2, 32);
    uint o1 = (uint)__shfl_xor((int)wd3, 32);
    uint o2 = (uint)__shfl_xor((int)wd0, 32);
    uint o3 = (uint)__shfl_xor((int)wd1, 32);
    uint4v uv = { lh ? o0 : wd0, lh ? o1 : wd1,
                  lh ? wd2 : o2, lh ? wd3 : o3 };
    bf[0] = __builtin_bit_cast(bf16x8, uv);
  }
  {
    uint o0 = (uint)__shfl_xor((int)wd6, 32);
    uint o1 = (uint)__shfl_xor((int)wd7, 32);
    uint o2 = (uint)__shfl_xor((int)wd4, 32);
    uint o3 = (uint)__shfl_xor((int)wd5, 32);
    uint4v uv = { lh ? o0 : wd4, lh ? o1 : wd5,
                  lh ? wd6 : o2, lh ? wd7 : o3 };
    bf[1] = __builtin_bit_cast(bf16x8, uv);
  }
}

static __device__ __forceinline__ long wbase(int w) {
  int wi = w & 31;
  int hi = (w >> 5) & 31;
  int b  = w >> 10;
  return (((long)(b * 256 + hi * 8)) * 256 + wi * 8) * 256;
}

// async 16B/lane global->LDS DMA (LDS dest = wave-uniform base + lane*16)
static __device__ __forceinline__ void dma16(const float* gp, char* lp) {
  __builtin_amdgcn_global_load_lds(
      (const __attribute__((address_space(1))) uint*)gp,
      (__attribute__((address_space(3))) uint*)lp, 16, 0, 0);
}

// read bf16x8 A-frag from f32 x-strip (swizzle: granule p = g ^ (tok&31))
static __device__ __forceinline__ bf16x8 ldax(const char* xs, int tok, int g) {
  const int sw = tok & 31;
  f32x4 u = *(const f32x4*)(xs + tok * 1024 + ((g ^ sw) << 4));
  f32x4 v = *(const f32x4*)(xs + tok * 1024 + (((g + 1) ^ sw) << 4));
  bf16x8 r;
  r[0] = (__bf16)u.x; r[1] = (__bf16)u.y; r[2] = (__bf16)u.z; r[3] = (__bf16)u.w;
  r[4] = (__bf16)v.x; r[5] = (__bf16)v.y; r[6] = (__bf16)v.z; r[7] = (__bf16)v.w;
  return r;
}

// ---------------- Main kernel ----------------
// LDS 144KB: x-f32 strips at 0 / 65536; attn-bf16 strips at 131072 / 139264.
__global__ __launch_bounds__(512, 2)
void na_msa_kernel(const float* __restrict__ x,
                   const float* __restrict__ attn,
                   const __bf16* __restrict__ WT,
                   const float* __restrict__ bo,
                   float* __restrict__ out) {
  __shared__ char lds[147456];

  const int t    = threadIdx.x;
  const int lane = t & 63;
  const int wvi  = t >> 6;              // wave 0..7, owns ch [32wvi, 32wvi+32)
  const int ln31 = lane & 31;
  const int lh   = lane >> 5;

  const __bf16* wtp = WT + (wvi * 32 + ln31) * 256 + 8 * lh;
  const float bv = bo[wvi * 32 + ln31];

  // attn staging geometry: thread t handles f32x4 idx {t, 512+t}
  const int arow0 = t >> 4;             // row for chunk 0 (chunk 1: +32)
  const int ak0   = (t & 15) * 4;

  const int w0 = blockIdx.x * 16;

#define STAGE_X(W, BUFOFF) do {                                            \
    const float* xp_ = x + wbase(W);                                       \
    _Pragma("unroll")                                                      \
    for (int j = 0; j < 8; ++j) {                                          \
      int tok_ = j * 8 + wvi;                                              \
      int ch0_ = (lane ^ (tok_ & 31)) * 4;                                 \
      const float* gp_ = xp_ + (tok_ >> 3) * 65536 + (tok_ & 7) * 256 + ch0_; \
      int off_ = __builtin_amdgcn_readfirstlane((BUFOFF) + j * 8192 + wvi * 1024); \
      dma16(gp_, lds + off_);                                              \
    } } while (0)

#define AWR(BAT, R0, R1) do {                                              \
    *(bf16x4*)((BAT) + arow0 * 128 + ((ak0 * 2) ^ ((arow0 & 7) << 4))) =   \
        bf16x4{ (__bf16)(R0).x, (__bf16)(R0).y, (__bf16)(R0).z, (__bf16)(R0).w }; \
    int row1_ = 32 + arow0;                                                \
    *(bf16x4*)((BAT) + row1_ * 128 + ((ak0 * 2) ^ ((row1_ & 7) << 4))) =   \
        bf16x4{ (__bf16)(R1).x, (__bf16)(R1).y, (__bf16)(R1).z, (__bf16)(R1).w }; \
    } while (0)

  // ---- prologue: hoist the 16 loop-invariant WT b0 frags into VGPRs ----
  bf16x8 wb[16];
#pragma unroll
  for (int ks = 0; ks < 16; ++ks) wb[ks] = *(const bf16x8*)(wtp + ks * 16);

  // ---- prologue: stage window w0 (attn first, then x DMAs) ----
  {
    const float* ap = attn + (long)w0 * 4096;
    f32x4 a0 = *(const f32x4*)(ap + t * 4);
    f32x4 a1 = *(const f32x4*)(ap + (512 + t) * 4);
    AWR(lds + 131072, a0, a1);
    STAGE_X(w0, 0);
  }
  asm volatile("s_waitcnt vmcnt(0) lgkmcnt(0)" ::: "memory");
  __builtin_amdgcn_s_barrier();
  __builtin_amdgcn_sched_barrier(0);

#pragma unroll 1
  for (int i = 0; i < 16; ++i) {
    const int w = w0 + i;
    const char* xs = lds + (i & 1) * 65536;
    const char* as = lds + 131072 + (i & 1) * 8192;

    // ---- next window staging: attn load+cvt+write FIRST (its compiler
    // wait sees only the attn loads), THEN the x DMAs (untracked). ----
    if (i < 15) {
      const float* ap = attn + (long)(w + 1) * 4096;
      f32x4 ra0 = *(const f32x4*)(ap + t * 4);
      f32x4 ra1 = *(const f32x4*)(ap + (512 + t) * 4);
      AWR(lds + 131072 + ((i + 1) & 1) * 8192, ra0, ra1);
      STAGE_X(w + 1, ((i + 1) & 1) * 65536);
    }
    __builtin_amdgcn_sched_barrier(0);   // pin: all issues before GEMM1

    // ---- GEMM1: z = xw @ W, K=256. Pure LDS+VALU+MFMA (b0 from regs!) ----
    f32x16 acc0 = {}, acc1 = {};
#pragma unroll
    for (int ks = 0; ks < 16; ++ks) {
      int g = 4 * ks + 2 * lh;
      bf16x8 a0 = ldax(xs, ln31, g);            // toks 0..31
      bf16x8 a1 = ldax(xs, 32 + ln31, g);       // toks 32..63
      acc0 = MFMA32(a0, wb[ks], acc0);
      acc1 = MFMA32(a1, wb[ks], acc1);
    }

    // ---- GEMM2 B-frags in-register ----
    bf16x8 bfr[4];
    build_bfrags(acc0, lh, &bfr[0]);
    build_bfrags(acc1, lh, &bfr[2]);

    // ---- GEMM2: out = attn @ z, K=64 (attn bf16 LDS) ----
    f32x16 o0 = {}, o1 = {};
#pragma unroll
    for (int ks = 0; ks < 4; ++ks) {
      int kk = ks * 16 + 8 * lh;
      int ab0 = ln31 * 128 + ((kk * 2) ^ ((ln31 & 7) << 4));
      bf16x8 a0 = *(const bf16x8*)(as + ab0);
      bf16x8 a1 = *(const bf16x8*)(as + ab0 + 4096);
      o0 = MFMA32(a0, bfr[ks], o0);
      o1 = MFMA32(a1, bfr[ks], o1);
    }

    // ---- epilogue: + bo, scatter-store window w (32 dword stores) ----
    {
      float* op = out + wbase(w);
      const int ch = wvi * 32 + ln31;
#pragma unroll
      for (int r = 0; r < 16; ++r) {
        int tok = (r & 3) + 8 * (r >> 2) + 4 * lh;
        op[(tok >> 3) * 65536 + (tok & 7) * 256 + ch] = o0[r] + bv;
      }
#pragma unroll
      for (int r = 0; r < 16; ++r) {
        int tok = 32 + (r & 3) + 8 * (r >> 2) + 4 * lh;
        op[(tok >> 3) * 65536 + (tok & 7) * 256 + ch] = o1[r] + bv;
      }
    }

    // ---- counted drain: stores (newest 32) ride; DMAs+attn (older) forced.
    asm volatile("s_waitcnt vmcnt(32) lgkmcnt(0)" ::: "memory");
    __builtin_amdgcn_s_barrier();
    __builtin_amdgcn_sched_barrier(0);
  }
#undef STAGE_X
#undef AWR
}

extern "C" void kernel_launch(void* const* d_in, const int* in_sizes, int n_in,
                              void* d_out, int out_size, void* d_ws, size_t ws_size,
                              hipStream_t stream) {
  const float* x    = (const float*)d_in[0];
  const float* attn = (const float*)d_in[1];
  const float* Wv   = (const float*)d_in[2];
  const float* Wo   = (const float*)d_in[3];
  const float* bo   = (const float*)d_in[4];
  float* out = (float*)d_out;
  __bf16* WT = (__bf16*)d_ws;   // 256*256*2 = 128 KB scratch

  wfuse_kernel<<<256, 256, 0, stream>>>(Wv, Wo, WT);
  na_msa_kernel<<<256, 512, 0, stream>>>(x, attn, WT, bo, out);
}

// Round 14
// 156.147 us; speedup vs baseline: 1.2442x; 1.0110x over previous
//
#include <hip/hip_runtime.h>
#include <hip/hip_bf16.h>

// NA Spatial MSA, fused:  out = attn @ (xw @ (Wv@Wo)) + bo
// R14 = R13 + attn-AWR moved AFTER the store phase.
// R13 proved the vmcnt-interference theory (WT hoist: 173->158). But R13
// placed the attn cvt+ds_write BEFORE the x DMAs -> a compiler vmcnt wait
// for the just-issued attn loads sat on the critical path (1 HBM RTT/window)
// and delayed DMA issue. Now: attn loads (oldest) -> DMAs -> compute (no
// waits) -> stores -> AWR (waits only attn: cheap vmcnt(40), DMAs+stores
// ride) -> vmcnt(32) barrier (stores ride, DMAs forced).

typedef __bf16 bf16x8 __attribute__((ext_vector_type(8)));
typedef __bf16 bf16x4 __attribute__((ext_vector_type(4)));
typedef float  f32x16 __attribute__((ext_vector_type(16)));
typedef float  f32x4  __attribute__((ext_vector_type(4)));
typedef unsigned int uint;
typedef uint   uint4v __attribute__((ext_vector_type(4)));

#define MFMA32(a, b, c) __builtin_amdgcn_mfma_f32_32x32x16_bf16(a, b, c, 0, 0, 0)

// ---------------- Stage 0: WT = (Wv @ Wo)^T in bf16 ----------------
__global__ void wfuse_kernel(const float* __restrict__ Wv,
                             const float* __restrict__ Wo,
                             __bf16* __restrict__ WT) {
  const int n = blockIdx.x;
  const int k = threadIdx.x;
  const float* wvrow = Wv + k * 256;
  float acc = 0.f;
#pragma unroll 4
  for (int j = 0; j < 256; j += 4) {
    f32x4 wv = *(const f32x4*)(wvrow + j);
    acc += wv.x * Wo[(j + 0) * 256 + n];
    acc += wv.y * Wo[(j + 1) * 256 + n];
    acc += wv.z * Wo[(j + 2) * 256 + n];
    acc += wv.w * Wo[(j + 3) * 256 + n];
  }
  WT[n * 256 + k] = (__bf16)acc;
}

static __device__ __forceinline__ uint pkbf(float lo, float hi) {
  return (uint)__builtin_bit_cast(unsigned short, (__bf16)lo) |
         ((uint)__builtin_bit_cast(unsigned short, (__bf16)hi) << 16);
}

// GEMM2 B-frags from GEMM1 acc via pack + shfl_xor(32). (verified R3/R5/R7)
static __device__ __forceinline__ void build_bfrags(const f32x16 acc, int lh,
                                                    bf16x8* bf) {
  uint wd0 = pkbf(acc[0],  acc[1]);
  uint wd1 = pkbf(acc[2],  acc[3]);
  uint wd2 = pkbf(acc[4],  acc[5]);
  uint wd3 = pkbf(acc[6],  acc[7]);
  uint wd4 = pkbf(acc[8],  acc[9]);
  uint wd5 = pkbf(acc[10], acc[11]);
  uint wd6 = pkbf(acc[12], acc[13]);
  uint wd7 = pkbf(acc[14], acc[15]);
  {
    uint o0 = (uint)__shfl_xor((int)wd2, 32);
    uint o1 = (uint)__shfl_xor((int)wd3, 32);
    uint o2 = (uint)__shfl_xor((int)wd0, 32);
    uint o3 = (uint)__shfl_xor((int)wd1, 32);
    uint4v uv = { lh ? o0 : wd0, lh ? o1 : wd1,
                  lh ? wd2 : o2, lh ? wd3 : o3 };
    bf[0] = __builtin_bit_cast(bf16x8, uv);
  }
  {
    uint o0 = (uint)__shfl_xor((int)wd6, 32);
    uint o1 = (uint)__shfl_xor((int)wd7, 32);
    uint o2 = (uint)__shfl_xor((int)wd4, 32);
    uint o3 = (uint)__shfl_xor((int)wd5, 32);
    uint4v uv = { lh ? o0 : wd4, lh ? o1 : wd5,
                  lh ? wd6 : o2, lh ? wd7 : o3 };
    bf[1] = __builtin_bit_cast(bf16x8, uv);
  }
}

static __device__ __forceinline__ long wbase(int w) {
  int wi = w & 31;
  int hi = (w >> 5) & 31;
  int b  = w >> 10;
  return (((long)(b * 256 + hi * 8)) * 256 + wi * 8) * 256;
}

// async 16B/lane global->LDS DMA (LDS dest = wave-uniform base + lane*16)
static __device__ __forceinline__ void dma16(const float* gp, char* lp) {
  __builtin_amdgcn_global_load_lds(
      (const __attribute__((address_space(1))) uint*)gp,
      (__attribute__((address_space(3))) uint*)lp, 16, 0, 0);
}

// read bf16x8 A-frag from f32 x-strip (swizzle: granule p = g ^ (tok&31))
static __device__ __forceinline__ bf16x8 ldax(const char* xs, int tok, int g) {
  const int sw = tok & 31;
  f32x4 u = *(const f32x4*)(xs + tok * 1024 + ((g ^ sw) << 4));
  f32x4 v = *(const f32x4*)(xs + tok * 1024 + (((g + 1) ^ sw) << 4));
  bf16x8 r;
  r[0] = (__bf16)u.x; r[1] = (__bf16)u.y; r[2] = (__bf16)u.z; r[3] = (__bf16)u.w;
  r[4] = (__bf16)v.x; r[5] = (__bf16)v.y; r[6] = (__bf16)v.z; r[7] = (__bf16)v.w;
  return r;
}

// ---------------- Main kernel ----------------
// LDS 144KB: x-f32 strips at 0 / 65536; attn-bf16 strips at 131072 / 139264.
__global__ __launch_bounds__(512, 2)
void na_msa_kernel(const float* __restrict__ x,
                   const float* __restrict__ attn,
                   const __bf16* __restrict__ WT,
                   const float* __restrict__ bo,
                   float* __restrict__ out) {
  __shared__ char lds[147456];

  const int t    = threadIdx.x;
  const int lane = t & 63;
  const int wvi  = t >> 6;              // wave 0..7, owns ch [32wvi, 32wvi+32)
  const int ln31 = lane & 31;
  const int lh   = lane >> 5;

  const __bf16* wtp = WT + (wvi * 32 + ln31) * 256 + 8 * lh;
  const float bv = bo[wvi * 32 + ln31];

  // attn staging geometry: thread t handles f32x4 idx {t, 512+t}
  const int arow0 = t >> 4;             // row for chunk 0 (chunk 1: +32)
  const int ak0   = (t & 15) * 4;

  const int w0 = blockIdx.x * 16;

#define STAGE_X(W, BUFOFF) do {                                            \
    const float* xp_ = x + wbase(W);                                       \
    _Pragma("unroll")                                                      \
    for (int j = 0; j < 8; ++j) {                                          \
      int tok_ = j * 8 + wvi;                                              \
      int ch0_ = (lane ^ (tok_ & 31)) * 4;                                 \
      const float* gp_ = xp_ + (tok_ >> 3) * 65536 + (tok_ & 7) * 256 + ch0_; \
      int off_ = __builtin_amdgcn_readfirstlane((BUFOFF) + j * 8192 + wvi * 1024); \
      dma16(gp_, lds + off_);                                              \
    } } while (0)

#define AWR(BAT, R0, R1) do {                                              \
    *(bf16x4*)((BAT) + arow0 * 128 + ((ak0 * 2) ^ ((arow0 & 7) << 4))) =   \
        bf16x4{ (__bf16)(R0).x, (__bf16)(R0).y, (__bf16)(R0).z, (__bf16)(R0).w }; \
    int row1_ = 32 + arow0;                                                \
    *(bf16x4*)((BAT) + row1_ * 128 + ((ak0 * 2) ^ ((row1_ & 7) << 4))) =   \
        bf16x4{ (__bf16)(R1).x, (__bf16)(R1).y, (__bf16)(R1).z, (__bf16)(R1).w }; \
    } while (0)

  // ---- prologue: hoist the 16 loop-invariant WT b0 frags into VGPRs ----
  bf16x8 wb[16];
#pragma unroll
  for (int ks = 0; ks < 16; ++ks) wb[ks] = *(const bf16x8*)(wtp + ks * 16);

  // ---- prologue: stage window w0 (attn first, then x DMAs) ----
  {
    const float* ap = attn + (long)w0 * 4096;
    f32x4 a0 = *(const f32x4*)(ap + t * 4);
    f32x4 a1 = *(const f32x4*)(ap + (512 + t) * 4);
    AWR(lds + 131072, a0, a1);
    STAGE_X(w0, 0);
  }
  asm volatile("s_waitcnt vmcnt(0) lgkmcnt(0)" ::: "memory");
  __builtin_amdgcn_s_barrier();
  __builtin_amdgcn_sched_barrier(0);

#pragma unroll 1
  for (int i = 0; i < 16; ++i) {
    const int w = w0 + i;
    const char* xs = lds + (i & 1) * 65536;
    const char* as = lds + 131072 + (i & 1) * 8192;

    // ---- issue next window's attn loads (OLDEST ops; no wait here!) and
    // x DMAs. AWR happens after the stores -> nothing blocks compute. ----
    f32x4 ra0, ra1;
    if (i < 15) {
      const float* ap = attn + (long)(w + 1) * 4096;
      ra0 = *(const f32x4*)(ap + t * 4);
      ra1 = *(const f32x4*)(ap + (512 + t) * 4);
      STAGE_X(w + 1, ((i + 1) & 1) * 65536);
    }
    __builtin_amdgcn_sched_barrier(0);   // pin: all issues before GEMM1

    // ---- GEMM1: z = xw @ W, K=256. Pure LDS+VALU+MFMA (b0 from regs) ----
    f32x16 acc0 = {}, acc1 = {};
#pragma unroll
    for (int ks = 0; ks < 16; ++ks) {
      int g = 4 * ks + 2 * lh;
      bf16x8 a0 = ldax(xs, ln31, g);            // toks 0..31
      bf16x8 a1 = ldax(xs, 32 + ln31, g);       // toks 32..63
      acc0 = MFMA32(a0, wb[ks], acc0);
      acc1 = MFMA32(a1, wb[ks], acc1);
    }

    // ---- GEMM2 B-frags in-register ----
    bf16x8 bfr[4];
    build_bfrags(acc0, lh, &bfr[0]);
    build_bfrags(acc1, lh, &bfr[2]);

    // ---- GEMM2: out = attn @ z, K=64 (attn bf16 LDS) ----
    f32x16 o0 = {}, o1 = {};
#pragma unroll
    for (int ks = 0; ks < 4; ++ks) {
      int kk = ks * 16 + 8 * lh;
      int ab0 = ln31 * 128 + ((kk * 2) ^ ((ln31 & 7) << 4));
      bf16x8 a0 = *(const bf16x8*)(as + ab0);
      bf16x8 a1 = *(const bf16x8*)(as + ab0 + 4096);
      o0 = MFMA32(a0, bfr[ks], o0);
      o1 = MFMA32(a1, bfr[ks], o1);
    }

    // ---- epilogue: + bo, scatter-store window w (32 dword stores) ----
    {
      float* op = out + wbase(w);
      const int ch = wvi * 32 + ln31;
#pragma unroll
      for (int r = 0; r < 16; ++r) {
        int tok = (r & 3) + 8 * (r >> 2) + 4 * lh;
        op[(tok >> 3) * 65536 + (tok & 7) * 256 + ch] = o0[r] + bv;
      }
#pragma unroll
      for (int r = 0; r < 16; ++r) {
        int tok = 32 + (r & 3) + 8 * (r >> 2) + 4 * lh;
        op[(tok >> 3) * 65536 + (tok & 7) * 256 + ch] = o1[r] + bv;
      }
    }

    // ---- attn cvt + ds_write for w+1: waits ONLY the (long-done) attn
    // loads via a counted vmcnt(~40); DMAs and stores keep riding. ----
    if (i < 15) {
      AWR(lds + 131072 + ((i + 1) & 1) * 8192, ra0, ra1);
    }

    // ---- counted drain: stores (newest 32) ride; DMAs (older) forced. ----
    asm volatile("s_waitcnt vmcnt(32) lgkmcnt(0)" ::: "memory");
    __builtin_amdgcn_s_barrier();
    __builtin_amdgcn_sched_barrier(0);
  }
#undef STAGE_X
#undef AWR
}

extern "C" void kernel_launch(void* const* d_in, const int* in_sizes, int n_in,
                              void* d_out, int out_size, void* d_ws, size_t ws_size,
                              hipStream_t stream) {
  const float* x    = (const float*)d_in[0];
  const float* attn = (const float*)d_in[1];
  const float* Wv   = (const float*)d_in[2];
  const float* Wo   = (const float*)d_in[3];
  const float* bo   = (const float*)d_in[4];
  float* out = (float*)d_out;
  __bf16* WT = (__bf16*)d_ws;   // 256*256*2 = 128 KB scratch

  wfuse_kernel<<<256, 256, 0, stream>>>(Wv, Wo, WT);
  na_msa_kernel<<<256, 512, 0, stream>>>(x, attn, WT, bo, out);
}